// Round 28
// baseline (405.037 us; speedup 1.0000x reference)
//
#include <hip/hip_runtime.h>
#include <cstdint>
#include <cstddef>

#define NN 50000
#define NNP 50016          // y2 row stride per group (row NN = zero row)
#define EE 800000
#define INF 512
#define HH  256
#define CC  10
#define NB2 391            // ceil(2*NN/256) scan blocks
#define NTB 782            // ceil(NN/64)  tail blocks per graph
#define GB64 782           // ceil(NN/64)  gemm blocks per graph
#define SPMM_BLOCKS 1600   // 200 blocks per column group x 8 groups (per graph)
#define HBIN 6250          // histogram bins per range task (25KB LDS)
#define HRNG 8             // ranges per array (8*6250 = NN)
#define HSUB 32            // sub-blocks per task
#define SCAP 1536
#define ZROW NN            // zero-row index within a y2 group slice
#define CAST_TOT (INF * HH + HH * HH + 16 * HH + 16 * HH)

using bfrag = __attribute__((ext_vector_type(8))) __bf16;
using f32x4 = __attribute__((ext_vector_type(4))) float;
using f32x2 = __attribute__((ext_vector_type(2))) float;

__device__ inline unsigned short f2bf(float x) {
    unsigned u = __builtin_bit_cast(unsigned, x);
    unsigned r = u + 0x7FFFu + ((u >> 16) & 1u);
    return (unsigned short)(r >> 16);
}
__device__ inline float bf2f(unsigned short h) {
    return __builtin_bit_cast(float, (unsigned)h << 16);
}

__device__ inline void gload_lds16(const void* gsrc, void* ldst) {
    __builtin_amdgcn_global_load_lds(
        (const __attribute__((address_space(1))) void*)gsrc,
        (__attribute__((address_space(3))) void*)ldst, 16, 0, 0);
}

// ---------------------------------------------------------------- merged weight casts
__global__ void k_cast_all(const float* __restrict__ W0, const float* __restrict__ W1,
                           const float* __restrict__ Wfc, const float* __restrict__ Wd,
                           ushort* __restrict__ W0t, ushort* __restrict__ W1t,
                           ushort* __restrict__ Wt1, ushort* __restrict__ Wt2) {
    int idx = blockIdx.x * blockDim.x + threadIdx.x;
    if (idx < INF * HH) {
        int n = idx / INF, k = idx % INF;
        W0t[idx] = f2bf(W0[(size_t)k * HH + n]);
    } else if (idx < INF * HH + HH * HH) {
        int j = idx - INF * HH;
        int n = j / HH, k = j % HH;
        W1t[j] = f2bf(W1[(size_t)k * HH + n]);
    } else if (idx < INF * HH + HH * HH + 16 * HH) {
        int j = idx - INF * HH - HH * HH;
        int n = j >> 8, k = j & 255;
        float v = 0.f;
        if (n < 10)       v = Wfc[(size_t)k * 10 + n];
        else if (n < 12)  v = Wd[(size_t)(HH + k) * 2 + (n - 10)];
        Wt1[j] = f2bf(v);
    } else if (idx < CAST_TOT) {
        int j = idx - INF * HH - HH * HH - 16 * HH;
        int n = j >> 8, k = j & 255;
        float v = (n < 2) ? Wd[(size_t)k * 2 + n] : 0.f;
        Wt2[j] = f2bf(v);
    }
}

// ---------------------------------------------------------------- LDS histogram degrees
__global__ __launch_bounds__(256) void k_deghist(
        const int* __restrict__ src_s, const int* __restrict__ dst_s,
        const int* __restrict__ src_t, const int* __restrict__ dst_t,
        ushort* __restrict__ pcnt) {
    __shared__ int hist[HBIN];
    const int task = blockIdx.x >> 5;    // 0..31
    const int sub  = blockIdx.x & 31;    // 0..31
    const int arr = task >> 3, range = task & 7;
    const int* p = (arr == 0) ? src_s : (arr == 1) ? dst_s : (arr == 2) ? src_t : dst_t;
    const int4* p4 = reinterpret_cast<const int4*>(p);
    const int lo = range * HBIN;
    for (int j = threadIdx.x; j < HBIN; j += 256) hist[j] = 0;
    __syncthreads();
    for (int i = sub * 256 + (int)threadIdx.x; i < EE / 4; i += HSUB * 256) {
        int4 v = p4[i];
        int a0 = v.x - lo, a1 = v.y - lo, a2 = v.z - lo, a3 = v.w - lo;
        if ((unsigned)a0 < (unsigned)HBIN) atomicAdd(&hist[a0], 1);
        if ((unsigned)a1 < (unsigned)HBIN) atomicAdd(&hist[a1], 1);
        if ((unsigned)a2 < (unsigned)HBIN) atomicAdd(&hist[a2], 1);
        if ((unsigned)a3 < (unsigned)HBIN) atomicAdd(&hist[a3], 1);
    }
    __syncthreads();
    ushort* out = pcnt + ((size_t)task * HSUB + sub) * HBIN;
    for (int j = threadIdx.x; j < HBIN; j += 256) out[j] = (ushort)hist[j];
}

__global__ void k_degsum(const ushort* __restrict__ pcnt, int* __restrict__ cnt) {
    int g = blockIdx.x * blockDim.x + threadIdx.x;
    if (g >= 4 * NN) return;
    int arr = g / NN;
    int node = g - arr * NN;
    int range = node / HBIN;
    int j = node - range * HBIN;
    const ushort* p = pcnt + ((size_t)(arr * HRNG + range) * HSUB) * HBIN + j;
    int s = 0;
    #pragma unroll
    for (int k = 0; k < HSUB; ++k) s += p[(size_t)k * HBIN];
    cnt[g] = s;
}

// ------------------------------------------------- 3-phase scan over in-degrees (2NN)
__global__ void k_scan_blk(const int* __restrict__ cnt, int* __restrict__ off,
                           int* __restrict__ btot) {
    __shared__ int wsum[4];
    int tid = threadIdx.x, lane = tid & 63, wid = tid >> 6;
    int i = blockIdx.x * 256 + tid;
    int v = 0;
    if (i < 2 * NN) v = (i < NN) ? cnt[NN + i] : cnt[2 * NN + i];
    int s = v;
    #pragma unroll
    for (int o = 1; o < 64; o <<= 1) {
        int t = __shfl_up(s, o, 64);
        if (lane >= o) s += t;
    }
    if (lane == 63) wsum[wid] = s;
    __syncthreads();
    if (tid == 0) {
        int a = 0;
        #pragma unroll
        for (int w2 = 0; w2 < 4; ++w2) { int t = wsum[w2]; wsum[w2] = a; a += t; }
        btot[blockIdx.x] = a;
    }
    __syncthreads();
    if (i < 2 * NN) off[i] = wsum[wid] + s - v;
}

__global__ void k_scan_tops(const int* __restrict__ btot, int* __restrict__ bbase,
                            int* __restrict__ off) {
    __shared__ int wsum[8];
    int tid = threadIdx.x, lane = tid & 63, wid = tid >> 6;
    int v = (tid < NB2) ? btot[tid] : 0;
    int s = v;
    #pragma unroll
    for (int o = 1; o < 64; o <<= 1) {
        int t = __shfl_up(s, o, 64);
        if (lane >= o) s += t;
    }
    if (lane == 63) wsum[wid] = s;
    __syncthreads();
    if (tid == 0) {
        int a = 0;
        #pragma unroll
        for (int w2 = 0; w2 < 8; ++w2) { int t = wsum[w2]; wsum[w2] = a; a += t; }
        off[2 * NN] = a;
    }
    __syncthreads();
    if (tid < NB2) bbase[tid] = wsum[wid] + s - v;
}

// fixup + norms + zero-row init + per-sub start positions (degpos folded in)
__global__ void k_scan_fin(int* __restrict__ off, const int* __restrict__ bbase,
                           const int* __restrict__ cnt,
                           float* __restrict__ ns, float* __restrict__ nd,
                           ushort* __restrict__ y2,
                           const ushort* __restrict__ pcnt, int* __restrict__ base2) {
    if (blockIdx.x == 0) {
        #pragma unroll
        for (int j = 0; j < 2; ++j) {
            int idx = j * 256 + (int)threadIdx.x;   // 0..511 = (graph, grp, col)
            int gg = idx >> 8, grp = (idx >> 5) & 7, c = idx & 31;
            y2[(((size_t)gg * 8 + grp) * NNP + ZROW) * 32 + c] = 0;
        }
    }
    int i = blockIdx.x * blockDim.x + threadIdx.x;
    if (i >= 2 * NN) return;
    int o = off[i] + bbase[i >> 8];
    off[i] = o;
    int co = (i < NN) ? cnt[i] : cnt[NN + i];          // out-degree
    int ci = (i < NN) ? cnt[NN + i] : cnt[2 * NN + i]; // in-degree
    ns[i] = 1.0f / sqrtf(fmaxf((float)co, 1.0f));
    nd[i] = 1.0f / sqrtf(fmaxf((float)ci, 1.0f));
    // degpos: per-sub start positions for the atomic-free fill
    int g = (i < NN) ? 0 : 1;
    int node = i - g * NN;
    int range = node / HBIN;
    int bin = node - range * HBIN;
    int arr = g ? 3 : 1;                 // dst_s / dst_t tasks
    const ushort* p = pcnt + ((size_t)(arr * HRNG + range) * HSUB) * HBIN + bin;
    int* b = base2 + ((size_t)(g * HRNG + range) * HSUB) * HBIN + bin;
    int run = o;
    #pragma unroll
    for (int s = 0; s < HSUB; ++s) {
        b[(size_t)s * HBIN] = run;
        run += p[(size_t)s * HBIN];
    }
}

// ------------------------------------------------- CSR fill, LDS-atomic only
__global__ __launch_bounds__(256) void k_fill3(
        const int* __restrict__ src_s, const int* __restrict__ dst_s,
        const int* __restrict__ src_t, const int* __restrict__ dst_t,
        const int* __restrict__ base2, int* __restrict__ csr_src) {
    __shared__ int cur[HBIN];
    const int combo = blockIdx.x & 15;   // g*8 + range
    const int sub = blockIdx.x >> 4;     // 0..31
    const int g = combo >> 3, range = combo & 7;
    const int4* d4 = reinterpret_cast<const int4*>(g ? dst_t : dst_s);
    const int4* s4 = reinterpret_cast<const int4*>(g ? src_t : src_s);
    const int lo = range * HBIN;
    const int* b = base2 + (size_t)combo * HSUB * HBIN + (size_t)sub * HBIN;
    for (int j = threadIdx.x; j < HBIN; j += 256) cur[j] = b[j];
    __syncthreads();
    for (int i = sub * 256 + (int)threadIdx.x; i < EE / 4; i += HSUB * 256) {
        int4 d = d4[i];
        int b0 = d.x - lo, b1 = d.y - lo, b2 = d.z - lo, b3 = d.w - lo;
        bool o0 = (unsigned)b0 < (unsigned)HBIN;
        bool o1 = (unsigned)b1 < (unsigned)HBIN;
        bool o2 = (unsigned)b2 < (unsigned)HBIN;
        bool o3 = (unsigned)b3 < (unsigned)HBIN;
        if (o0 | o1 | o2 | o3) {
            int4 s = s4[i];
            if (o0) csr_src[atomicAdd(&cur[b0], 1)] = s.x;
            if (o1) csr_src[atomicAdd(&cur[b1], 1)] = s.y;
            if (o2) csr_src[atomicAdd(&cur[b2], 1)] = s.z;
            if (o3) csr_src[atomicAdd(&cur[b3], 1)] = s.w;
        }
    }
}

// ---------------------------------------------------------------- MFMA GEMM, both graphs
// BM=64, BN=256; grid 2*GB64. LDS-tiled coalesced epilogue with 16B-block
// XOR swizzle (blk ^= row&7). y2 layout [2][8][NNP][32].
template<int K, bool F32A>
__global__ __launch_bounds__(256, 4) void k_gemm2(
        const void* __restrict__ Ap_s, const void* __restrict__ Ap_t,
        const ushort* __restrict__ Bt, const float* __restrict__ ns2,
        ushort* __restrict__ y2) {
    __shared__ ushort As[64 * 64];      // 8KB
    __shared__ ushort Bs[256 * 64];     // 32KB (reused as 64x256 output tile)
    const int g = blockIdx.x >= GB64 ? 1 : 0;
    const void* Ap = g ? Ap_t : Ap_s;
    const float* ns = ns2 + (size_t)g * NN;
    ushort* y2g = y2 + (size_t)g * 8 * NNP * 32;
    const int m0 = (blockIdx.x - g * GB64) * 64;
    const int t = threadIdx.x;
    const int wid = t >> 6, lane = t & 63;
    const int wc = wid * 64;
    const int l15 = lane & 15, lg = lane >> 4;

    f32x4 acc[4][4];
    #pragma unroll
    for (int m = 0; m < 4; ++m)
        #pragma unroll
        for (int n = 0; n < 4; ++n)
            acc[m][n] = {0.f, 0.f, 0.f, 0.f};

    const int srow = t >> 3;
    const int schunk = t & 7;

    for (int k0 = 0; k0 < K; k0 += 64) {
        if constexpr (F32A) {
            #pragma unroll
            for (int i = 0; i < 2; ++i) {        // A tile 64x64, fp32->bf16 convert
                int row = srow + i * 32;
                int sw = ((schunk ^ (row & 7)) * 8);
                int m = m0 + row; if (m >= NN) m = NN - 1;
                const float* ap = (const float*)Ap + (size_t)m * K + k0 + schunk * 8;
                float4 f0 = *reinterpret_cast<const float4*>(ap);
                float4 f1 = *reinterpret_cast<const float4*>(ap + 4);
                uint4 va;
                va.x = (unsigned)f2bf(f0.x) | ((unsigned)f2bf(f0.y) << 16);
                va.y = (unsigned)f2bf(f0.z) | ((unsigned)f2bf(f0.w) << 16);
                va.z = (unsigned)f2bf(f1.x) | ((unsigned)f2bf(f1.y) << 16);
                va.w = (unsigned)f2bf(f1.z) | ((unsigned)f2bf(f1.w) << 16);
                *reinterpret_cast<uint4*>(&As[row * 64 + sw]) = va;
            }
        } else {
            #pragma unroll
            for (int i = 0; i < 2; ++i) {        // A tile 64x64, direct to LDS
                int row = srow + i * 32;
                int sw = ((schunk ^ (row & 7)) * 8);
                int m = m0 + row; if (m >= NN) m = NN - 1;
                const ushort* gsrc = (const ushort*)Ap + (size_t)m * K + k0 + sw;
                gload_lds16(gsrc, &As[(size_t)(wid * 8 + i * 32) * 64]);
            }
        }
        #pragma unroll
        for (int i = 0; i < 8; ++i) {            // B tile 256x64, direct to LDS
            int row = srow + i * 32;
            int sw = ((schunk ^ (row & 7)) * 8);
            const ushort* gsrc = &Bt[(size_t)row * K + k0 + sw];
            gload_lds16(gsrc, &Bs[(size_t)(wid * 8 + i * 32) * 64]);
        }
        __syncthreads();
        #pragma unroll
        for (int kk = 0; kk < 64; kk += 32) {
            const int kc = kk >> 3;
            bfrag af[4];
            #pragma unroll
            for (int m = 0; m < 4; ++m) {
                int row = m * 16 + l15;
                af[m] = *reinterpret_cast<const bfrag*>(&As[row * 64 + (((lg + kc) ^ (row & 7)) * 8)]);
            }
            #pragma unroll
            for (int n = 0; n < 4; ++n) {
                int row = wc + n * 16 + l15;
                bfrag bg = *reinterpret_cast<const bfrag*>(&Bs[row * 64 + (((lg + kc) ^ (row & 7)) * 8)]);
                #pragma unroll
                for (int m = 0; m < 4; ++m)
                    acc[m][n] = __builtin_amdgcn_mfma_f32_16x16x32_bf16(af[m], bg, acc[m][n], 0, 0, 0);
            }
        }
        __syncthreads();
    }

    // ---- epilogue: acc -> swizzled LDS tile (64x256 bf16) -> coalesced stores
    ushort* tile = Bs;
    #pragma unroll
    for (int m = 0; m < 4; ++m) {
        #pragma unroll
        for (int r = 0; r < 4; ++r) {
            int rloc = m * 16 + lg * 4 + r;
            int rowg = m0 + rloc;
            float nsv = ns[rowg < NN ? rowg : NN - 1];
            #pragma unroll
            for (int n = 0; n < 4; ++n) {
                int col = wc + n * 16 + l15;
                int blk = (col >> 3) ^ (rloc & 7);   // 16B-block swizzle
                tile[rloc * 256 + (blk << 3) + (col & 7)] = f2bf(acc[m][n][r] * nsv);
            }
        }
    }
    __syncthreads();
    {
        int row = t >> 2, sub = t & 3;
        int m = m0 + row;
        if (m < NN) {
            #pragma unroll
            for (int grp = 0; grp < 8; ++grp) {
                int blk = (grp * 4 + sub) ^ (row & 7);
                uint4 v = *reinterpret_cast<const uint4*>(&tile[row * 256 + (blk << 3)]);
                *reinterpret_cast<uint4*>(&y2g[((size_t)grp * NNP + m) * 32 + sub * 8]) = v;
            }
        }
    }
}

// ------------------------------------------------- SpMM: both graphs, branchless,
// 4-deep pipeline (16 loads in flight), packed f32x2 accumulation.
__device__ inline void add8p(f32x2* a, uint4 v) {
    f32x2 p;
    p.x = __builtin_bit_cast(float, v.x << 16);
    p.y = __builtin_bit_cast(float, v.x & 0xffff0000u);
    a[0] += p;
    p.x = __builtin_bit_cast(float, v.y << 16);
    p.y = __builtin_bit_cast(float, v.y & 0xffff0000u);
    a[1] += p;
    p.x = __builtin_bit_cast(float, v.z << 16);
    p.y = __builtin_bit_cast(float, v.z & 0xffff0000u);
    a[2] += p;
    p.x = __builtin_bit_cast(float, v.w << 16);
    p.y = __builtin_bit_cast(float, v.w & 0xffff0000u);
    a[3] += p;
}

__global__ __launch_bounds__(256) void k_spmm7(
        const ushort* __restrict__ y2, const int* __restrict__ off2,
        const int* __restrict__ csr_src, const float* __restrict__ nd2,
        const float* __restrict__ bias, ushort* __restrict__ h_s,
        ushort* __restrict__ h_t) {
    __shared__ int sidx[4][SCAP];
    const int gsel = blockIdx.x >= SPMM_BLOCKS ? 1 : 0;
    const int bid = blockIdx.x - gsel * SPMM_BLOCKS;
    const int* off = off2 + (size_t)gsel * NN;
    const float* nd_arr = nd2 + (size_t)gsel * NN;
    const ushort* y2g = y2 + (size_t)gsel * 8 * NNP * 32;
    ushort* h_out = gsel ? h_t : h_s;

    const int grp = bid & 7;
    const int blk = bid >> 3;                 // 0..199
    const int tid = threadIdx.x;
    const int lane = tid & 63, wid = tid >> 6;
    const int slot = lane >> 2;               // 0..15
    const int sub = lane & 3;                 // 16B sub-chunk of the 32-col slice
    const ushort* ybase = y2g + (size_t)grp * NNP * 32 + sub * 8;

    const int nb = (blk * 4 + wid) * 64;
    int s_wave0 = 0, cnt = 0;
    if (nb < NN) {
        int nend = nb + 64 < NN ? nb + 64 : NN;
        s_wave0 = off[nb];
        cnt = off[nend] - s_wave0;
    }
    int stage = cnt < SCAP ? cnt : SCAP;
    for (int j = lane; j < stage; j += 64)
        sidx[wid][j] = csr_src[s_wave0 + j];
    __syncthreads();

    float bia[8];
    #pragma unroll
    for (int j = 0; j < 8; ++j) bia[j] = bias[grp * 32 + sub * 8 + j];

    int e0[4], e1[4];
    f32x2 a[4][4];
    #pragma unroll
    for (int c = 0; c < 4; ++c) {
        int n = nb + c * 16 + slot;
        bool v = n < NN;
        e0[c] = v ? off[n] - s_wave0 : 0;
        e1[c] = v ? off[n + 1] - s_wave0 : 0;
        #pragma unroll
        for (int j = 0; j < 4; ++j) a[c][j] = {0.f, 0.f};
    }
    int tmax = max(max(e1[0] - e0[0], e1[1] - e0[1]), max(e1[2] - e0[2], e1[3] - e0[3]));

    if (cnt <= SCAP) {
        for (int t = 0; t < tmax; t += 4) {
            uint4 v[16];
            #pragma unroll
            for (int u = 0; u < 4; ++u)
                #pragma unroll
                for (int c = 0; c < 4; ++c) {
                    int ec = e0[c] + t + u;
                    bool val = ec < e1[c];
                    int ecc = val ? ec : 0;
                    int id = sidx[wid][ecc];
                    id = val ? id : ZROW;
                    v[u * 4 + c] = *reinterpret_cast<const uint4*>(&ybase[(size_t)id * 32]);
                }
            #pragma unroll
            for (int u = 0; u < 4; ++u)
                #pragma unroll
                for (int c = 0; c < 4; ++c) add8p(a[c], v[u * 4 + c]);
        }
    } else {
        for (int t = 0; t < tmax; t += 4) {
            uint4 v[16];
            #pragma unroll
            for (int u = 0; u < 4; ++u)
                #pragma unroll
                for (int c = 0; c < 4; ++c) {
                    int ec = e0[c] + t + u;
                    bool val = ec < e1[c];
                    int ecc = val ? ec : 0;
                    int id = csr_src[s_wave0 + ecc];
                    id = val ? id : ZROW;
                    v[u * 4 + c] = *reinterpret_cast<const uint4*>(&ybase[(size_t)id * 32]);
                }
            #pragma unroll
            for (int u = 0; u < 4; ++u)
                #pragma unroll
                for (int c = 0; c < 4; ++c) add8p(a[c], v[u * 4 + c]);
        }
    }

    #pragma unroll
    for (int c = 0; c < 4; ++c) {
        int n = nb + c * 16 + slot;
        if (n >= NN) continue;
        float nd = nd_arr[n];
        ushort r[8];
        #pragma unroll
        for (int j = 0; j < 8; ++j) {
            float av = (j & 1) ? a[c][j >> 1].y : a[c][j >> 1].x;
            r[j] = f2bf(fmaxf(av * nd + bia[j], 0.f));
        }
        uint4 pk;
        pk.x = (unsigned)r[0] | ((unsigned)r[1] << 16);
        pk.y = (unsigned)r[2] | ((unsigned)r[3] << 16);
        pk.z = (unsigned)r[4] | ((unsigned)r[5] << 16);
        pk.w = (unsigned)r[6] | ((unsigned)r[7] << 16);
        *reinterpret_cast<uint4*>(&h_out[(size_t)n * 256 + grp * 32 + sub * 8]) = pk;
    }
}

// ------------------------------------------------- MFMA tail, both graphs
__global__ __launch_bounds__(256) void k_tail_mfma(
        const ushort* __restrict__ h0s, const ushort* __restrict__ h0t,
        const ushort* __restrict__ h1s, const ushort* __restrict__ h1t,
        const ushort* __restrict__ Wt1, const ushort* __restrict__ Wt2,
        const float* __restrict__ bfc, const float* __restrict__ bd,
        const int* __restrict__ labels,
        float* __restrict__ pcls, float* __restrict__ pdom) {
    __shared__ float sT1[4][16][17];
    __shared__ float sT2[4][16][17];
    __shared__ float sc[4], sd[4];
    const int g = blockIdx.x >= NTB ? 1 : 0;
    const int bi = blockIdx.x - g * NTB;
    const ushort* h0 = g ? h0t : h0s;
    const ushort* h1 = g ? h1t : h1s;
    const int tid = threadIdx.x;
    const int wid = tid >> 6, lane = tid & 63;
    const int l15 = lane & 15, lg = lane >> 4;
    const int base = bi * 64 + wid * 16;

    int arow = base + l15; if (arow >= NN) arow = NN - 1;
    const ushort* a1 = h1 + (size_t)arow * 256 + lg * 8;
    const ushort* a0 = h0 + (size_t)arow * 256 + lg * 8;
    const ushort* b1 = Wt1 + (size_t)l15 * 256 + lg * 8;
    const ushort* b2 = Wt2 + (size_t)l15 * 256 + lg * 8;
    f32x4 acc1 = {0.f, 0.f, 0.f, 0.f};
    f32x4 acc2 = {0.f, 0.f, 0.f, 0.f};
    #pragma unroll
    for (int kk = 0; kk < 8; ++kk) {
        bfrag af1 = *reinterpret_cast<const bfrag*>(a1 + kk * 32);
        bfrag bg1 = *reinterpret_cast<const bfrag*>(b1 + kk * 32);
        acc1 = __builtin_amdgcn_mfma_f32_16x16x32_bf16(af1, bg1, acc1, 0, 0, 0);
        bfrag af0 = *reinterpret_cast<const bfrag*>(a0 + kk * 32);
        bfrag bg2 = *reinterpret_cast<const bfrag*>(b2 + kk * 32);
        acc2 = __builtin_amdgcn_mfma_f32_16x16x32_bf16(af0, bg2, acc2, 0, 0, 0);
    }
    #pragma unroll
    for (int j = 0; j < 4; ++j) {
        sT1[wid][lg * 4 + j][l15] = acc1[j];
        sT2[wid][lg * 4 + j][l15] = acc2[j];
    }
    __syncthreads();

    float cls = 0.f, dom = 0.f;
    int n = base + lane;
    if (lane < 16 && n < NN) {
        float lgt[10];
        #pragma unroll
        for (int c = 0; c < 10; ++c) lgt[c] = sT1[wid][lane][c] + bfc[c];
        float dl0 = bd[0] + sT2[wid][lane][0] + sT1[wid][lane][10];
        float dl1 = bd[1] + sT2[wid][lane][1] + sT1[wid][lane][11];
        if (g == 0) {
            float m = lgt[0];
            #pragma unroll
            for (int c = 1; c < 10; ++c) m = fmaxf(m, lgt[c]);
            float s = 0.f;
            #pragma unroll
            for (int c = 0; c < 10; ++c) s += expf(lgt[c] - m);
            int lab = labels[n];
            float tgt = lgt[0];
            #pragma unroll
            for (int c = 1; c < 10; ++c) tgt = (c == lab) ? lgt[c] : tgt;
            cls = -(tgt - (m + logf(s)));
        }
        float m2 = fmaxf(dl0, dl1);
        float lse2 = m2 + logf(expf(dl0 - m2) + expf(dl1 - m2));
        dom = -((g ? dl1 : dl0) - lse2);
    }
    #pragma unroll
    for (int o = 1; o < 16; o <<= 1) {
        cls += __shfl_xor(cls, o, 64);
        dom += __shfl_xor(dom, o, 64);
    }
    if (lane == 0) { sc[wid] = cls; sd[wid] = dom; }
    __syncthreads();
    if (tid == 0) {
        float c = sc[0] + sc[1] + sc[2] + sc[3];
        float d = sd[0] + sd[1] + sd[2] + sd[3];
        if (g == 0) pcls[bi] = c;
        pdom[g * NTB + bi] = d;
    }
}

__global__ void k_finalize(const float* __restrict__ pcls, const float* __restrict__ pdom,
                           float* __restrict__ out) {
    __shared__ float sc[4], sd[4];
    int tid = threadIdx.x, lane = tid & 63, wid = tid >> 6;
    float c = 0.f, d = 0.f;
    for (int i = tid; i < NTB; i += 256) c += pcls[i];
    for (int i = tid; i < 2 * NTB; i += 256) d += pdom[i];
    #pragma unroll
    for (int o = 32; o; o >>= 1) {
        c += __shfl_xor(c, o, 64);
        d += __shfl_xor(d, o, 64);
    }
    if (lane == 0) { sc[wid] = c; sd[wid] = d; }
    __syncthreads();
    if (tid == 0) {
        float ct = sc[0] + sc[1] + sc[2] + sc[3];
        float dt = sd[0] + sd[1] + sd[2] + sd[3];
        out[0] = ct / (float)NN + 0.01f * (dt / (float)(2 * NN));
    }
}

// ---------------------------------------------------------------- launch
extern "C" void kernel_launch(void* const* d_in, const int* in_sizes, int n_in,
                              void* d_out, int out_size, void* d_ws, size_t ws_size,
                              hipStream_t stream) {
    const float* features_s = (const float*)d_in[0];
    const int*   labels_s   = (const int*)d_in[1];
    const float* features_t = (const float*)d_in[2];
    const int*   src_s      = (const int*)d_in[3];
    const int*   dst_s      = (const int*)d_in[4];
    const int*   src_t      = (const int*)d_in[5];
    const int*   dst_t      = (const int*)d_in[6];
    const float* W0         = (const float*)d_in[7];
    const float* b0         = (const float*)d_in[8];
    const float* W1         = (const float*)d_in[9];
    const float* b1         = (const float*)d_in[10];
    const float* Wfc        = (const float*)d_in[11];
    const float* bfc        = (const float*)d_in[12];
    const float* Wd         = (const float*)d_in[13];
    const float* bd         = (const float*)d_in[14];
    float* out = (float*)d_out;

    auto align256 = [](size_t x) { return (x + 255) & ~(size_t)255; };
    char* w = (char*)d_ws;
    ushort* h0s    = (ushort*)w; w += align256((size_t)NN * HH * 2);       // 25.6 MB
    ushort* h0t    = (ushort*)w; w += align256((size_t)NN * HH * 2);       // 25.6 MB
    ushort* h1s    = (ushort*)w; w += align256((size_t)NN * HH * 2);       // 25.6 MB
    ushort* h1t    = (ushort*)w; w += align256((size_t)NN * HH * 2);       // 25.6 MB
    ushort* y2     = (ushort*)w; w += align256((size_t)2 * 8 * NNP * 32 * 2); // 51.2 MB
    ushort* W0t    = (ushort*)w; w += align256((size_t)INF * HH * 2);
    ushort* W1t    = (ushort*)w; w += align256((size_t)HH * HH * 2);
    ushort* Wt1    = (ushort*)w; w += align256((size_t)16 * HH * 2);
    ushort* Wt2    = (ushort*)w; w += align256((size_t)16 * HH * 2);
    float* ns      = (float*)w;  w += align256((size_t)2 * NN * 4);
    float* nd      = (float*)w;  w += align256((size_t)2 * NN * 4);
    int*   cnt     = (int*)w;    w += align256((size_t)4 * NN * 4);
    int*   csr_off = (int*)w;    w += align256((size_t)(2 * NN + 1) * 4);
    int*   csr_src = (int*)w;    w += align256((size_t)2 * EE * 4);        // 6.4 MB
    int*   btot    = (int*)w;    w += align256((size_t)NB2 * 4);
    int*   bbase   = (int*)w;    w += align256((size_t)NB2 * 4);
    float* pcls    = (float*)w;  w += align256((size_t)NTB * 4);
    float* pdom    = (float*)w;  w += align256((size_t)2 * NTB * 4);
    ushort* pcnt   = (ushort*)w; w += align256((size_t)4 * HRNG * HSUB * HBIN * 2); // 12.8 MB
    int*   base2   = (int*)w;    w += align256((size_t)2 * HRNG * HSUB * HBIN * 4); // 12.8 MB

    const int TB = 256;
    k_cast_all<<<(CAST_TOT + TB - 1) / TB, TB, 0, stream>>>(W0, W1, Wfc, Wd,
                                                            W0t, W1t, Wt1, Wt2);

    // batched CSR prep (no global atomics anywhere)
    k_deghist<<<4 * HRNG * HSUB, TB, 0, stream>>>(src_s, dst_s, src_t, dst_t, pcnt);
    k_degsum<<<(4 * NN + TB - 1) / TB, TB, 0, stream>>>(pcnt, cnt);
    k_scan_blk<<<NB2, TB, 0, stream>>>(cnt, csr_off, btot);
    k_scan_tops<<<1, 512, 0, stream>>>(btot, bbase, csr_off);
    k_scan_fin<<<NB2, TB, 0, stream>>>(csr_off, bbase, cnt, ns, nd, y2, pcnt, base2);
    k_fill3<<<16 * HSUB, TB, 0, stream>>>(src_s, dst_s, src_t, dst_t, base2, csr_src);

    // layer 0 (both graphs per dispatch)
    k_gemm2<INF, true><<<2 * GB64, TB, 0, stream>>>(features_s, features_t, W0t, ns, y2);
    k_spmm7<<<2 * SPMM_BLOCKS, TB, 0, stream>>>(y2, csr_off, csr_src, nd, b0, h0s, h0t);

    // layer 1
    k_gemm2<HH, false><<<2 * GB64, TB, 0, stream>>>(h0s, h0t, W1t, ns, y2);
    k_spmm7<<<2 * SPMM_BLOCKS, TB, 0, stream>>>(y2, csr_off, csr_src, nd, b1, h1s, h1t);

    // tail: fc + dlog + losses for both graphs
    k_tail_mfma<<<2 * NTB, TB, 0, stream>>>(h0s, h0t, h1s, h1t, Wt1, Wt2, bfc, bd,
                                            labels_s, pcls, pdom);
    k_finalize<<<1, TB, 0, stream>>>(pcls, pdom, out);
}

// Round 29
// 395.517 us; speedup vs baseline: 1.0241x; 1.0241x over previous
//
#include <hip/hip_runtime.h>
#include <cstdint>
#include <cstddef>

#define NN 50000
#define NNP 50016          // y2 row stride per group (row NN = zero row)
#define EE 800000
#define INF 512
#define HH  256
#define CC  10
#define NB2 391            // ceil(2*NN/256) scan blocks
#define NTB 782            // ceil(NN/64)  tail blocks per graph
#define GB64 782           // ceil(NN/64)  gemm blocks per graph
#define SPMM_BLOCKS 1600   // 200 blocks per column group x 8 groups (per graph)
#define HBIN 6250          // histogram bins per range task (25KB LDS)
#define HRNG 8             // ranges per array (8*6250 = NN)
#define HSUB 32            // sub-blocks per task
#define SCAP 1536
#define ZROW NN            // zero-row index within a y2 group slice
#define CAST_TOT (INF * HH + HH * HH + 16 * HH + 16 * HH)

using bfrag = __attribute__((ext_vector_type(8))) __bf16;
using f32x4 = __attribute__((ext_vector_type(4))) float;
using f32x2 = __attribute__((ext_vector_type(2))) float;

__device__ inline unsigned short f2bf(float x) {
    unsigned u = __builtin_bit_cast(unsigned, x);
    unsigned r = u + 0x7FFFu + ((u >> 16) & 1u);
    return (unsigned short)(r >> 16);
}
__device__ inline float bf2f(unsigned short h) {
    return __builtin_bit_cast(float, (unsigned)h << 16);
}

__device__ inline void gload_lds16(const void* gsrc, void* ldst) {
    __builtin_amdgcn_global_load_lds(
        (const __attribute__((address_space(1))) void*)gsrc,
        (__attribute__((address_space(3))) void*)ldst, 16, 0, 0);
}

// ---------------------------------------------------------------- merged weight casts
__global__ void k_cast_all(const float* __restrict__ W0, const float* __restrict__ W1,
                           const float* __restrict__ Wfc, const float* __restrict__ Wd,
                           ushort* __restrict__ W0t, ushort* __restrict__ W1t,
                           ushort* __restrict__ Wt1, ushort* __restrict__ Wt2) {
    int idx = blockIdx.x * blockDim.x + threadIdx.x;
    if (idx < INF * HH) {
        int n = idx / INF, k = idx % INF;
        W0t[idx] = f2bf(W0[(size_t)k * HH + n]);
    } else if (idx < INF * HH + HH * HH) {
        int j = idx - INF * HH;
        int n = j / HH, k = j % HH;
        W1t[j] = f2bf(W1[(size_t)k * HH + n]);
    } else if (idx < INF * HH + HH * HH + 16 * HH) {
        int j = idx - INF * HH - HH * HH;
        int n = j >> 8, k = j & 255;
        float v = 0.f;
        if (n < 10)       v = Wfc[(size_t)k * 10 + n];
        else if (n < 12)  v = Wd[(size_t)(HH + k) * 2 + (n - 10)];
        Wt1[j] = f2bf(v);
    } else if (idx < CAST_TOT) {
        int j = idx - INF * HH - HH * HH - 16 * HH;
        int n = j >> 8, k = j & 255;
        float v = (n < 2) ? Wd[(size_t)k * 2 + n] : 0.f;
        Wt2[j] = f2bf(v);
    }
}

// ---------------------------------------------------------------- LDS histogram degrees
__global__ __launch_bounds__(256) void k_deghist(
        const int* __restrict__ src_s, const int* __restrict__ dst_s,
        const int* __restrict__ src_t, const int* __restrict__ dst_t,
        ushort* __restrict__ pcnt) {
    __shared__ int hist[HBIN];
    const int task = blockIdx.x >> 5;    // 0..31
    const int sub  = blockIdx.x & 31;    // 0..31
    const int arr = task >> 3, range = task & 7;
    const int* p = (arr == 0) ? src_s : (arr == 1) ? dst_s : (arr == 2) ? src_t : dst_t;
    const int4* p4 = reinterpret_cast<const int4*>(p);
    const int lo = range * HBIN;
    for (int j = threadIdx.x; j < HBIN; j += 256) hist[j] = 0;
    __syncthreads();
    for (int i = sub * 256 + (int)threadIdx.x; i < EE / 4; i += HSUB * 256) {
        int4 v = p4[i];
        int a0 = v.x - lo, a1 = v.y - lo, a2 = v.z - lo, a3 = v.w - lo;
        if ((unsigned)a0 < (unsigned)HBIN) atomicAdd(&hist[a0], 1);
        if ((unsigned)a1 < (unsigned)HBIN) atomicAdd(&hist[a1], 1);
        if ((unsigned)a2 < (unsigned)HBIN) atomicAdd(&hist[a2], 1);
        if ((unsigned)a3 < (unsigned)HBIN) atomicAdd(&hist[a3], 1);
    }
    __syncthreads();
    ushort* out = pcnt + ((size_t)task * HSUB + sub) * HBIN;
    for (int j = threadIdx.x; j < HBIN; j += 256) out[j] = (ushort)hist[j];
}

__global__ void k_degsum(const ushort* __restrict__ pcnt, int* __restrict__ cnt) {
    int g = blockIdx.x * blockDim.x + threadIdx.x;
    if (g >= 4 * NN) return;
    int arr = g / NN;
    int node = g - arr * NN;
    int range = node / HBIN;
    int j = node - range * HBIN;
    const ushort* p = pcnt + ((size_t)(arr * HRNG + range) * HSUB) * HBIN + j;
    int s = 0;
    #pragma unroll
    for (int k = 0; k < HSUB; ++k) s += p[(size_t)k * HBIN];
    cnt[g] = s;
}

// ------------------------------------------------- 3-phase scan over in-degrees (2NN)
__global__ void k_scan_blk(const int* __restrict__ cnt, int* __restrict__ off,
                           int* __restrict__ btot) {
    __shared__ int wsum[4];
    int tid = threadIdx.x, lane = tid & 63, wid = tid >> 6;
    int i = blockIdx.x * 256 + tid;
    int v = 0;
    if (i < 2 * NN) v = (i < NN) ? cnt[NN + i] : cnt[2 * NN + i];
    int s = v;
    #pragma unroll
    for (int o = 1; o < 64; o <<= 1) {
        int t = __shfl_up(s, o, 64);
        if (lane >= o) s += t;
    }
    if (lane == 63) wsum[wid] = s;
    __syncthreads();
    if (tid == 0) {
        int a = 0;
        #pragma unroll
        for (int w2 = 0; w2 < 4; ++w2) { int t = wsum[w2]; wsum[w2] = a; a += t; }
        btot[blockIdx.x] = a;
    }
    __syncthreads();
    if (i < 2 * NN) off[i] = wsum[wid] + s - v;
}

__global__ void k_scan_tops(const int* __restrict__ btot, int* __restrict__ bbase,
                            int* __restrict__ off) {
    __shared__ int wsum[8];
    int tid = threadIdx.x, lane = tid & 63, wid = tid >> 6;
    int v = (tid < NB2) ? btot[tid] : 0;
    int s = v;
    #pragma unroll
    for (int o = 1; o < 64; o <<= 1) {
        int t = __shfl_up(s, o, 64);
        if (lane >= o) s += t;
    }
    if (lane == 63) wsum[wid] = s;
    __syncthreads();
    if (tid == 0) {
        int a = 0;
        #pragma unroll
        for (int w2 = 0; w2 < 8; ++w2) { int t = wsum[w2]; wsum[w2] = a; a += t; }
        off[2 * NN] = a;
    }
    __syncthreads();
    if (tid < NB2) bbase[tid] = wsum[wid] + s - v;
}

// fixup + norms + zero-row init + per-sub start positions (degpos folded in)
__global__ void k_scan_fin(int* __restrict__ off, const int* __restrict__ bbase,
                           const int* __restrict__ cnt,
                           float* __restrict__ ns, float* __restrict__ nd,
                           ushort* __restrict__ y2,
                           const ushort* __restrict__ pcnt, int* __restrict__ base2) {
    if (blockIdx.x == 0) {
        #pragma unroll
        for (int j = 0; j < 2; ++j) {
            int idx = j * 256 + (int)threadIdx.x;   // 0..511 = (graph, grp, col)
            int gg = idx >> 8, grp = (idx >> 5) & 7, c = idx & 31;
            y2[(((size_t)gg * 8 + grp) * NNP + ZROW) * 32 + c] = 0;
        }
    }
    int i = blockIdx.x * blockDim.x + threadIdx.x;
    if (i >= 2 * NN) return;
    int o = off[i] + bbase[i >> 8];
    off[i] = o;
    int co = (i < NN) ? cnt[i] : cnt[NN + i];          // out-degree
    int ci = (i < NN) ? cnt[NN + i] : cnt[2 * NN + i]; // in-degree
    ns[i] = 1.0f / sqrtf(fmaxf((float)co, 1.0f));
    nd[i] = 1.0f / sqrtf(fmaxf((float)ci, 1.0f));
    // degpos: per-sub start positions for the atomic-free fill
    int g = (i < NN) ? 0 : 1;
    int node = i - g * NN;
    int range = node / HBIN;
    int bin = node - range * HBIN;
    int arr = g ? 3 : 1;                 // dst_s / dst_t tasks
    const ushort* p = pcnt + ((size_t)(arr * HRNG + range) * HSUB) * HBIN + bin;
    int* b = base2 + ((size_t)(g * HRNG + range) * HSUB) * HBIN + bin;
    int run = o;
    #pragma unroll
    for (int s = 0; s < HSUB; ++s) {
        b[(size_t)s * HBIN] = run;
        run += p[(size_t)s * HBIN];
    }
}

// ------------------------------------------------- CSR fill, LDS-atomic only
__global__ __launch_bounds__(256) void k_fill3(
        const int* __restrict__ src_s, const int* __restrict__ dst_s,
        const int* __restrict__ src_t, const int* __restrict__ dst_t,
        const int* __restrict__ base2, int* __restrict__ csr_src) {
    __shared__ int cur[HBIN];
    const int combo = blockIdx.x & 15;   // g*8 + range
    const int sub = blockIdx.x >> 4;     // 0..31
    const int g = combo >> 3, range = combo & 7;
    const int4* d4 = reinterpret_cast<const int4*>(g ? dst_t : dst_s);
    const int4* s4 = reinterpret_cast<const int4*>(g ? src_t : src_s);
    const int lo = range * HBIN;
    const int* b = base2 + (size_t)combo * HSUB * HBIN + (size_t)sub * HBIN;
    for (int j = threadIdx.x; j < HBIN; j += 256) cur[j] = b[j];
    __syncthreads();
    for (int i = sub * 256 + (int)threadIdx.x; i < EE / 4; i += HSUB * 256) {
        int4 d = d4[i];
        int b0 = d.x - lo, b1 = d.y - lo, b2 = d.z - lo, b3 = d.w - lo;
        bool o0 = (unsigned)b0 < (unsigned)HBIN;
        bool o1 = (unsigned)b1 < (unsigned)HBIN;
        bool o2 = (unsigned)b2 < (unsigned)HBIN;
        bool o3 = (unsigned)b3 < (unsigned)HBIN;
        if (o0 | o1 | o2 | o3) {
            int4 s = s4[i];
            if (o0) csr_src[atomicAdd(&cur[b0], 1)] = s.x;
            if (o1) csr_src[atomicAdd(&cur[b1], 1)] = s.y;
            if (o2) csr_src[atomicAdd(&cur[b2], 1)] = s.z;
            if (o3) csr_src[atomicAdd(&cur[b3], 1)] = s.w;
        }
    }
}

// ---------------------------------------------------------------- MFMA GEMM, both graphs
// BM=64, BN=256; grid 2*GB64. LDS-tiled coalesced epilogue with 16B-block
// XOR swizzle (blk ^= row&7). y2 layout [2][8][NNP][32].
template<int K, bool F32A>
__global__ __launch_bounds__(256, 4) void k_gemm2(
        const void* __restrict__ Ap_s, const void* __restrict__ Ap_t,
        const ushort* __restrict__ Bt, const float* __restrict__ ns2,
        ushort* __restrict__ y2) {
    __shared__ ushort As[64 * 64];      // 8KB
    __shared__ ushort Bs[256 * 64];     // 32KB (reused as 64x256 output tile)
    const int g = blockIdx.x >= GB64 ? 1 : 0;
    const void* Ap = g ? Ap_t : Ap_s;
    const float* ns = ns2 + (size_t)g * NN;
    ushort* y2g = y2 + (size_t)g * 8 * NNP * 32;
    const int m0 = (blockIdx.x - g * GB64) * 64;
    const int t = threadIdx.x;
    const int wid = t >> 6, lane = t & 63;
    const int wc = wid * 64;
    const int l15 = lane & 15, lg = lane >> 4;

    f32x4 acc[4][4];
    #pragma unroll
    for (int m = 0; m < 4; ++m)
        #pragma unroll
        for (int n = 0; n < 4; ++n)
            acc[m][n] = {0.f, 0.f, 0.f, 0.f};

    const int srow = t >> 3;
    const int schunk = t & 7;

    for (int k0 = 0; k0 < K; k0 += 64) {
        if constexpr (F32A) {
            #pragma unroll
            for (int i = 0; i < 2; ++i) {        // A tile 64x64, fp32->bf16 convert
                int row = srow + i * 32;
                int sw = ((schunk ^ (row & 7)) * 8);
                int m = m0 + row; if (m >= NN) m = NN - 1;
                const float* ap = (const float*)Ap + (size_t)m * K + k0 + schunk * 8;
                float4 f0 = *reinterpret_cast<const float4*>(ap);
                float4 f1 = *reinterpret_cast<const float4*>(ap + 4);
                uint4 va;
                va.x = (unsigned)f2bf(f0.x) | ((unsigned)f2bf(f0.y) << 16);
                va.y = (unsigned)f2bf(f0.z) | ((unsigned)f2bf(f0.w) << 16);
                va.z = (unsigned)f2bf(f1.x) | ((unsigned)f2bf(f1.y) << 16);
                va.w = (unsigned)f2bf(f1.z) | ((unsigned)f2bf(f1.w) << 16);
                *reinterpret_cast<uint4*>(&As[row * 64 + sw]) = va;
            }
        } else {
            #pragma unroll
            for (int i = 0; i < 2; ++i) {        // A tile 64x64, direct to LDS
                int row = srow + i * 32;
                int sw = ((schunk ^ (row & 7)) * 8);
                int m = m0 + row; if (m >= NN) m = NN - 1;
                const ushort* gsrc = (const ushort*)Ap + (size_t)m * K + k0 + sw;
                gload_lds16(gsrc, &As[(size_t)(wid * 8 + i * 32) * 64]);
            }
        }
        #pragma unroll
        for (int i = 0; i < 8; ++i) {            // B tile 256x64, direct to LDS
            int row = srow + i * 32;
            int sw = ((schunk ^ (row & 7)) * 8);
            const ushort* gsrc = &Bt[(size_t)row * K + k0 + sw];
            gload_lds16(gsrc, &Bs[(size_t)(wid * 8 + i * 32) * 64]);
        }
        __syncthreads();
        #pragma unroll
        for (int kk = 0; kk < 64; kk += 32) {
            const int kc = kk >> 3;
            bfrag af[4];
            #pragma unroll
            for (int m = 0; m < 4; ++m) {
                int row = m * 16 + l15;
                af[m] = *reinterpret_cast<const bfrag*>(&As[row * 64 + (((lg + kc) ^ (row & 7)) * 8)]);
            }
            #pragma unroll
            for (int n = 0; n < 4; ++n) {
                int row = wc + n * 16 + l15;
                bfrag bg = *reinterpret_cast<const bfrag*>(&Bs[row * 64 + (((lg + kc) ^ (row & 7)) * 8)]);
                #pragma unroll
                for (int m = 0; m < 4; ++m)
                    acc[m][n] = __builtin_amdgcn_mfma_f32_16x16x32_bf16(af[m], bg, acc[m][n], 0, 0, 0);
            }
        }
        __syncthreads();
    }

    // ---- epilogue: acc -> swizzled LDS tile (64x256 bf16) -> coalesced stores
    ushort* tile = Bs;
    #pragma unroll
    for (int m = 0; m < 4; ++m) {
        #pragma unroll
        for (int r = 0; r < 4; ++r) {
            int rloc = m * 16 + lg * 4 + r;
            int rowg = m0 + rloc;
            float nsv = ns[rowg < NN ? rowg : NN - 1];
            #pragma unroll
            for (int n = 0; n < 4; ++n) {
                int col = wc + n * 16 + l15;
                int blk = (col >> 3) ^ (rloc & 7);   // 16B-block swizzle
                tile[rloc * 256 + (blk << 3) + (col & 7)] = f2bf(acc[m][n][r] * nsv);
            }
        }
    }
    __syncthreads();
    {
        int row = t >> 2, sub = t & 3;
        int m = m0 + row;
        if (m < NN) {
            #pragma unroll
            for (int grp = 0; grp < 8; ++grp) {
                int blk = (grp * 4 + sub) ^ (row & 7);
                uint4 v = *reinterpret_cast<const uint4*>(&tile[row * 256 + (blk << 3)]);
                *reinterpret_cast<uint4*>(&y2g[((size_t)grp * NNP + m) * 32 + sub * 8]) = v;
            }
        }
    }
}

// ------------------------------------------------- SpMM: both graphs, branchless,
// 2-deep pipeline, packed f32x2 accumulation (v_pk_add_f32).
__device__ inline void add8p(f32x2* a, uint4 v) {
    f32x2 p;
    p.x = __builtin_bit_cast(float, v.x << 16);
    p.y = __builtin_bit_cast(float, v.x & 0xffff0000u);
    a[0] += p;
    p.x = __builtin_bit_cast(float, v.y << 16);
    p.y = __builtin_bit_cast(float, v.y & 0xffff0000u);
    a[1] += p;
    p.x = __builtin_bit_cast(float, v.z << 16);
    p.y = __builtin_bit_cast(float, v.z & 0xffff0000u);
    a[2] += p;
    p.x = __builtin_bit_cast(float, v.w << 16);
    p.y = __builtin_bit_cast(float, v.w & 0xffff0000u);
    a[3] += p;
}

__global__ __launch_bounds__(256) void k_spmm7(
        const ushort* __restrict__ y2, const int* __restrict__ off2,
        const int* __restrict__ csr_src, const float* __restrict__ nd2,
        const float* __restrict__ bias, ushort* __restrict__ h_s,
        ushort* __restrict__ h_t) {
    __shared__ int sidx[4][SCAP];
    const int gsel = blockIdx.x >= SPMM_BLOCKS ? 1 : 0;
    const int bid = blockIdx.x - gsel * SPMM_BLOCKS;
    const int* off = off2 + (size_t)gsel * NN;
    const float* nd_arr = nd2 + (size_t)gsel * NN;
    const ushort* y2g = y2 + (size_t)gsel * 8 * NNP * 32;
    ushort* h_out = gsel ? h_t : h_s;

    const int grp = bid & 7;
    const int blk = bid >> 3;                 // 0..199
    const int tid = threadIdx.x;
    const int lane = tid & 63, wid = tid >> 6;
    const int slot = lane >> 2;               // 0..15
    const int sub = lane & 3;                 // 16B sub-chunk of the 32-col slice
    const ushort* ybase = y2g + (size_t)grp * NNP * 32 + sub * 8;

    const int nb = (blk * 4 + wid) * 64;
    int s_wave0 = 0, cnt = 0;
    if (nb < NN) {
        int nend = nb + 64 < NN ? nb + 64 : NN;
        s_wave0 = off[nb];
        cnt = off[nend] - s_wave0;
    }
    int stage = cnt < SCAP ? cnt : SCAP;
    for (int j = lane; j < stage; j += 64)
        sidx[wid][j] = csr_src[s_wave0 + j];
    __syncthreads();

    float bia[8];
    #pragma unroll
    for (int j = 0; j < 8; ++j) bia[j] = bias[grp * 32 + sub * 8 + j];

    int e0[4], e1[4];
    f32x2 a[4][4];
    #pragma unroll
    for (int c = 0; c < 4; ++c) {
        int n = nb + c * 16 + slot;
        bool v = n < NN;
        e0[c] = v ? off[n] - s_wave0 : 0;
        e1[c] = v ? off[n + 1] - s_wave0 : 0;
        #pragma unroll
        for (int j = 0; j < 4; ++j) a[c][j] = {0.f, 0.f};
    }
    int tmax = max(max(e1[0] - e0[0], e1[1] - e0[1]), max(e1[2] - e0[2], e1[3] - e0[3]));

    if (cnt <= SCAP) {
        for (int t = 0; t < tmax; t += 2) {
            uint4 v[8];
            #pragma unroll
            for (int u = 0; u < 2; ++u)
                #pragma unroll
                for (int c = 0; c < 4; ++c) {
                    int ec = e0[c] + t + u;
                    bool val = ec < e1[c];
                    int ecc = val ? ec : 0;
                    int id = sidx[wid][ecc];
                    id = val ? id : ZROW;
                    v[u * 4 + c] = *reinterpret_cast<const uint4*>(&ybase[(size_t)id * 32]);
                }
            #pragma unroll
            for (int u = 0; u < 2; ++u)
                #pragma unroll
                for (int c = 0; c < 4; ++c) add8p(a[c], v[u * 4 + c]);
        }
    } else {
        for (int t = 0; t < tmax; t += 2) {
            uint4 v[8];
            #pragma unroll
            for (int u = 0; u < 2; ++u)
                #pragma unroll
                for (int c = 0; c < 4; ++c) {
                    int ec = e0[c] + t + u;
                    bool val = ec < e1[c];
                    int ecc = val ? ec : 0;
                    int id = csr_src[s_wave0 + ecc];
                    id = val ? id : ZROW;
                    v[u * 4 + c] = *reinterpret_cast<const uint4*>(&ybase[(size_t)id * 32]);
                }
            #pragma unroll
            for (int u = 0; u < 2; ++u)
                #pragma unroll
                for (int c = 0; c < 4; ++c) add8p(a[c], v[u * 4 + c]);
        }
    }

    #pragma unroll
    for (int c = 0; c < 4; ++c) {
        int n = nb + c * 16 + slot;
        if (n >= NN) continue;
        float nd = nd_arr[n];
        ushort r[8];
        #pragma unroll
        for (int j = 0; j < 8; ++j) {
            float av = (j & 1) ? a[c][j >> 1].y : a[c][j >> 1].x;
            r[j] = f2bf(fmaxf(av * nd + bia[j], 0.f));
        }
        uint4 pk;
        pk.x = (unsigned)r[0] | ((unsigned)r[1] << 16);
        pk.y = (unsigned)r[2] | ((unsigned)r[3] << 16);
        pk.z = (unsigned)r[4] | ((unsigned)r[5] << 16);
        pk.w = (unsigned)r[6] | ((unsigned)r[7] << 16);
        *reinterpret_cast<uint4*>(&h_out[(size_t)n * 256 + grp * 32 + sub * 8]) = pk;
    }
}

// ------------------------------------------------- MFMA tail, both graphs
__global__ __launch_bounds__(256) void k_tail_mfma(
        const ushort* __restrict__ h0s, const ushort* __restrict__ h0t,
        const ushort* __restrict__ h1s, const ushort* __restrict__ h1t,
        const ushort* __restrict__ Wt1, const ushort* __restrict__ Wt2,
        const float* __restrict__ bfc, const float* __restrict__ bd,
        const int* __restrict__ labels,
        float* __restrict__ pcls, float* __restrict__ pdom) {
    __shared__ float sT1[4][16][17];
    __shared__ float sT2[4][16][17];
    __shared__ float sc[4], sd[4];
    const int g = blockIdx.x >= NTB ? 1 : 0;
    const int bi = blockIdx.x - g * NTB;
    const ushort* h0 = g ? h0t : h0s;
    const ushort* h1 = g ? h1t : h1s;
    const int tid = threadIdx.x;
    const int wid = tid >> 6, lane = tid & 63;
    const int l15 = lane & 15, lg = lane >> 4;
    const int base = bi * 64 + wid * 16;

    int arow = base + l15; if (arow >= NN) arow = NN - 1;
    const ushort* a1 = h1 + (size_t)arow * 256 + lg * 8;
    const ushort* a0 = h0 + (size_t)arow * 256 + lg * 8;
    const ushort* b1 = Wt1 + (size_t)l15 * 256 + lg * 8;
    const ushort* b2 = Wt2 + (size_t)l15 * 256 + lg * 8;
    f32x4 acc1 = {0.f, 0.f, 0.f, 0.f};
    f32x4 acc2 = {0.f, 0.f, 0.f, 0.f};
    #pragma unroll
    for (int kk = 0; kk < 8; ++kk) {
        bfrag af1 = *reinterpret_cast<const bfrag*>(a1 + kk * 32);
        bfrag bg1 = *reinterpret_cast<const bfrag*>(b1 + kk * 32);
        acc1 = __builtin_amdgcn_mfma_f32_16x16x32_bf16(af1, bg1, acc1, 0, 0, 0);
        bfrag af0 = *reinterpret_cast<const bfrag*>(a0 + kk * 32);
        bfrag bg2 = *reinterpret_cast<const bfrag*>(b2 + kk * 32);
        acc2 = __builtin_amdgcn_mfma_f32_16x16x32_bf16(af0, bg2, acc2, 0, 0, 0);
    }
    #pragma unroll
    for (int j = 0; j < 4; ++j) {
        sT1[wid][lg * 4 + j][l15] = acc1[j];
        sT2[wid][lg * 4 + j][l15] = acc2[j];
    }
    __syncthreads();

    float cls = 0.f, dom = 0.f;
    int n = base + lane;
    if (lane < 16 && n < NN) {
        float lgt[10];
        #pragma unroll
        for (int c = 0; c < 10; ++c) lgt[c] = sT1[wid][lane][c] + bfc[c];
        float dl0 = bd[0] + sT2[wid][lane][0] + sT1[wid][lane][10];
        float dl1 = bd[1] + sT2[wid][lane][1] + sT1[wid][lane][11];
        if (g == 0) {
            float m = lgt[0];
            #pragma unroll
            for (int c = 1; c < 10; ++c) m = fmaxf(m, lgt[c]);
            float s = 0.f;
            #pragma unroll
            for (int c = 0; c < 10; ++c) s += expf(lgt[c] - m);
            int lab = labels[n];
            float tgt = lgt[0];
            #pragma unroll
            for (int c = 1; c < 10; ++c) tgt = (c == lab) ? lgt[c] : tgt;
            cls = -(tgt - (m + logf(s)));
        }
        float m2 = fmaxf(dl0, dl1);
        float lse2 = m2 + logf(expf(dl0 - m2) + expf(dl1 - m2));
        dom = -((g ? dl1 : dl0) - lse2);
    }
    #pragma unroll
    for (int o = 1; o < 16; o <<= 1) {
        cls += __shfl_xor(cls, o, 64);
        dom += __shfl_xor(dom, o, 64);
    }
    if (lane == 0) { sc[wid] = cls; sd[wid] = dom; }
    __syncthreads();
    if (tid == 0) {
        float c = sc[0] + sc[1] + sc[2] + sc[3];
        float d = sd[0] + sd[1] + sd[2] + sd[3];
        if (g == 0) pcls[bi] = c;
        pdom[g * NTB + bi] = d;
    }
}

__global__ void k_finalize(const float* __restrict__ pcls, const float* __restrict__ pdom,
                           float* __restrict__ out) {
    __shared__ float sc[4], sd[4];
    int tid = threadIdx.x, lane = tid & 63, wid = tid >> 6;
    float c = 0.f, d = 0.f;
    for (int i = tid; i < NTB; i += 256) c += pcls[i];
    for (int i = tid; i < 2 * NTB; i += 256) d += pdom[i];
    #pragma unroll
    for (int o = 32; o; o >>= 1) {
        c += __shfl_xor(c, o, 64);
        d += __shfl_xor(d, o, 64);
    }
    if (lane == 0) { sc[wid] = c; sd[wid] = d; }
    __syncthreads();
    if (tid == 0) {
        float ct = sc[0] + sc[1] + sc[2] + sc[3];
        float dt = sd[0] + sd[1] + sd[2] + sd[3];
        out[0] = ct / (float)NN + 0.01f * (dt / (float)(2 * NN));
    }
}

// ---------------------------------------------------------------- launch
extern "C" void kernel_launch(void* const* d_in, const int* in_sizes, int n_in,
                              void* d_out, int out_size, void* d_ws, size_t ws_size,
                              hipStream_t stream) {
    const float* features_s = (const float*)d_in[0];
    const int*   labels_s   = (const int*)d_in[1];
    const float* features_t = (const float*)d_in[2];
    const int*   src_s      = (const int*)d_in[3];
    const int*   dst_s      = (const int*)d_in[4];
    const int*   src_t      = (const int*)d_in[5];
    const int*   dst_t      = (const int*)d_in[6];
    const float* W0         = (const float*)d_in[7];
    const float* b0         = (const float*)d_in[8];
    const float* W1         = (const float*)d_in[9];
    const float* b1         = (const float*)d_in[10];
    const float* Wfc        = (const float*)d_in[11];
    const float* bfc        = (const float*)d_in[12];
    const float* Wd         = (const float*)d_in[13];
    const float* bd         = (const float*)d_in[14];
    float* out = (float*)d_out;

    auto align256 = [](size_t x) { return (x + 255) & ~(size_t)255; };
    char* w = (char*)d_ws;
    ushort* h0s    = (ushort*)w; w += align256((size_t)NN * HH * 2);       // 25.6 MB
    ushort* h0t    = (ushort*)w; w += align256((size_t)NN * HH * 2);       // 25.6 MB
    ushort* h1s    = (ushort*)w; w += align256((size_t)NN * HH * 2);       // 25.6 MB
    ushort* h1t    = (ushort*)w; w += align256((size_t)NN * HH * 2);       // 25.6 MB
    ushort* y2     = (ushort*)w; w += align256((size_t)2 * 8 * NNP * 32 * 2); // 51.2 MB
    ushort* W0t    = (ushort*)w; w += align256((size_t)INF * HH * 2);
    ushort* W1t    = (ushort*)w; w += align256((size_t)HH * HH * 2);
    ushort* Wt1    = (ushort*)w; w += align256((size_t)16 * HH * 2);
    ushort* Wt2    = (ushort*)w; w += align256((size_t)16 * HH * 2);
    float* ns      = (float*)w;  w += align256((size_t)2 * NN * 4);
    float* nd      = (float*)w;  w += align256((size_t)2 * NN * 4);
    int*   cnt     = (int*)w;    w += align256((size_t)4 * NN * 4);
    int*   csr_off = (int*)w;    w += align256((size_t)(2 * NN + 1) * 4);
    int*   csr_src = (int*)w;    w += align256((size_t)2 * EE * 4);        // 6.4 MB
    int*   btot    = (int*)w;    w += align256((size_t)NB2 * 4);
    int*   bbase   = (int*)w;    w += align256((size_t)NB2 * 4);
    float* pcls    = (float*)w;  w += align256((size_t)NTB * 4);
    float* pdom    = (float*)w;  w += align256((size_t)2 * NTB * 4);
    ushort* pcnt   = (ushort*)w; w += align256((size_t)4 * HRNG * HSUB * HBIN * 2); // 12.8 MB
    int*   base2   = (int*)w;    w += align256((size_t)2 * HRNG * HSUB * HBIN * 4); // 12.8 MB

    const int TB = 256;
    k_cast_all<<<(CAST_TOT + TB - 1) / TB, TB, 0, stream>>>(W0, W1, Wfc, Wd,
                                                            W0t, W1t, Wt1, Wt2);

    // batched CSR prep (no global atomics anywhere)
    k_deghist<<<4 * HRNG * HSUB, TB, 0, stream>>>(src_s, dst_s, src_t, dst_t, pcnt);
    k_degsum<<<(4 * NN + TB - 1) / TB, TB, 0, stream>>>(pcnt, cnt);
    k_scan_blk<<<NB2, TB, 0, stream>>>(cnt, csr_off, btot);
    k_scan_tops<<<1, 512, 0, stream>>>(btot, bbase, csr_off);
    k_scan_fin<<<NB2, TB, 0, stream>>>(csr_off, bbase, cnt, ns, nd, y2, pcnt, base2);
    k_fill3<<<16 * HSUB, TB, 0, stream>>>(src_s, dst_s, src_t, dst_t, base2, csr_src);

    // layer 0 (both graphs per dispatch)
    k_gemm2<INF, true><<<2 * GB64, TB, 0, stream>>>(features_s, features_t, W0t, ns, y2);
    k_spmm7<<<2 * SPMM_BLOCKS, TB, 0, stream>>>(y2, csr_off, csr_src, nd, b0, h0s, h0t);

    // layer 1
    k_gemm2<HH, false><<<2 * GB64, TB, 0, stream>>>(h0s, h0t, W1t, ns, y2);
    k_spmm7<<<2 * SPMM_BLOCKS, TB, 0, stream>>>(y2, csr_off, csr_src, nd, b1, h1s, h1t);

    // tail: fc + dlog + losses for both graphs
    k_tail_mfma<<<2 * NTB, TB, 0, stream>>>(h0s, h0t, h1s, h1t, Wt1, Wt2, bfc, bd,
                                            labels_s, pcls, pdom);
    k_finalize<<<1, TB, 0, stream>>>(pcls, pdom, out);
}